// Round 1
// baseline (66.422 us; speedup 1.0000x reference)
//
#include <hip/hip_runtime.h>

// InitMotionParams: out[p,n,i] = sum_j R(p,n)[i,j]*means[p,j] + T(p,n)[i]
// where R = cont_6d_to_rmat(sum_k softmax(coefs)[p,k] * motion_rots[k,ts[n],:])
//       T = sum_k softmax(coefs)[p,k] * motion_transls[k,ts[n],:]
// Key facts: K=20, B=8, G=400000. Table (B*K*9 floats) is shared by all
// gaussians -> LDS broadcast. Softmax normalization cancels in the rotation
// (Gram-Schmidt is scale-invariant) -> fold 1/sum only into the translation.

constexpr int KK  = 20;   // number of motion bases
constexpr int BB  = 8;    // number of timesteps
constexpr int GPT = 2;    // gaussians per thread (amortize LDS broadcasts)
constexpr int BLK = 256;

__global__ __launch_bounds__(BLK) void motion_fwd(
    const float* __restrict__ motion_rots,    // (K,F,6)
    const float* __restrict__ motion_transls, // (K,F,3)
    const float* __restrict__ motion_coefs,   // (G,K)
    const float* __restrict__ means,          // (G,3)
    const int*   __restrict__ ts,             // (B)
    float* __restrict__ out,                  // (G,B,3)
    int G, int F)
{
    // [0:6]=rot6d, [6:9]=transl, [9:12]=pad -> 48B rows, 16B-aligned
    __shared__ float tab[BB][KK][12];
    const int tid = threadIdx.x;
    if (tid < BB * KK) {
        const int n = tid / KK, k = tid % KK;
        const int t = ts[n];
        const float* rp = motion_rots    + ((size_t)k * F + t) * 6;
        const float* tp = motion_transls + ((size_t)k * F + t) * 3;
        float* dst = &tab[n][k][0];
        #pragma unroll
        for (int i = 0; i < 6; ++i) dst[i] = rp[i];
        #pragma unroll
        for (int i = 0; i < 3; ++i) dst[6 + i] = tp[i];
        dst[9] = dst[10] = dst[11] = 0.f;
    }
    __syncthreads();

    const long long pbase = ((long long)blockIdx.x * BLK + tid) * GPT;

    float w[GPT][KK];          // unnormalized softmax weights e^(c-max)
    float invs[GPT];           // 1/sum(e)
    float mx0[GPT], mx1[GPT], mx2[GPT];

    #pragma unroll
    for (int g = 0; g < GPT; ++g) {
        const long long p  = pbase + g;
        const long long pc = p < G ? p : (long long)G - 1;  // clamp for loads
        const float4* crow = reinterpret_cast<const float4*>(motion_coefs + pc * KK);
        float c[KK];
        #pragma unroll
        for (int q = 0; q < KK / 4; ++q) {
            const float4 v = crow[q];
            c[4*q+0] = v.x; c[4*q+1] = v.y; c[4*q+2] = v.z; c[4*q+3] = v.w;
        }
        float m = c[0];
        #pragma unroll
        for (int k = 1; k < KK; ++k) m = fmaxf(m, c[k]);
        float s = 0.f;
        #pragma unroll
        for (int k = 0; k < KK; ++k) {
            const float e = __expf(c[k] - m);
            w[g][k] = e;
            s += e;
        }
        invs[g] = __builtin_amdgcn_rcpf(s);
        mx0[g] = means[pc*3+0];
        mx1[g] = means[pc*3+1];
        mx2[g] = means[pc*3+2];
    }

    for (int n = 0; n < BB; ++n) {
        float acc[GPT][9];
        #pragma unroll
        for (int g = 0; g < GPT; ++g)
            #pragma unroll
            for (int i = 0; i < 9; ++i) acc[g][i] = 0.f;

        #pragma unroll
        for (int k = 0; k < KK; ++k) {
            const float4 A  = *reinterpret_cast<const float4*>(&tab[n][k][0]);
            const float4 Bv = *reinterpret_cast<const float4*>(&tab[n][k][4]);
            const float  Cv = tab[n][k][8];
            #pragma unroll
            for (int g = 0; g < GPT; ++g) {
                const float wk = w[g][k];
                acc[g][0] = fmaf(wk, A.x,  acc[g][0]);
                acc[g][1] = fmaf(wk, A.y,  acc[g][1]);
                acc[g][2] = fmaf(wk, A.z,  acc[g][2]);
                acc[g][3] = fmaf(wk, A.w,  acc[g][3]);
                acc[g][4] = fmaf(wk, Bv.x, acc[g][4]);
                acc[g][5] = fmaf(wk, Bv.y, acc[g][5]);
                acc[g][6] = fmaf(wk, Bv.z, acc[g][6]);
                acc[g][7] = fmaf(wk, Bv.w, acc[g][7]);
                acc[g][8] = fmaf(wk, Cv,   acc[g][8]);
            }
        }

        #pragma unroll
        for (int g = 0; g < GPT; ++g) {
            const long long p = pbase + g;
            const float r0 = acc[g][0], r1 = acc[g][1], r2 = acc[g][2];
            const float r3 = acc[g][3], r4 = acc[g][4], r5 = acc[g][5];

            // b1 = a1/max(|a1|,eps)   (scale-invariant: w unnormalized is fine)
            const float n1 = __builtin_amdgcn_sqrtf(fmaf(r0, r0, fmaf(r1, r1, r2*r2)));
            const float i1 = __builtin_amdgcn_rcpf(fmaxf(n1, 1e-12f));
            const float b10 = r0*i1, b11 = r1*i1, b12 = r2*i1;
            // a2p = a2 - (b1.a2) b1 ; b2 = a2p/max(|a2p|,eps)
            const float d  = fmaf(b10, r3, fmaf(b11, r4, b12*r5));
            const float a0 = fmaf(-d, b10, r3);
            const float a1 = fmaf(-d, b11, r4);
            const float a2 = fmaf(-d, b12, r5);
            const float n2 = __builtin_amdgcn_sqrtf(fmaf(a0, a0, fmaf(a1, a1, a2*a2)));
            const float i2 = __builtin_amdgcn_rcpf(fmaxf(n2, 1e-12f));
            const float b20 = a0*i2, b21 = a1*i2, b22 = a2*i2;
            // b3 = b1 x b2
            const float b30 = fmaf(b11, b22, -(b12*b21));
            const float b31 = fmaf(b12, b20, -(b10*b22));
            const float b32 = fmaf(b10, b21, -(b11*b20));
            // translation gets the deferred softmax normalization
            const float t0 = acc[g][6]*invs[g];
            const float t1 = acc[g][7]*invs[g];
            const float t2 = acc[g][8]*invs[g];

            const float o0 = fmaf(b10, mx0[g], fmaf(b20, mx1[g], fmaf(b30, mx2[g], t0)));
            const float o1 = fmaf(b11, mx0[g], fmaf(b21, mx1[g], fmaf(b31, mx2[g], t1)));
            const float o2 = fmaf(b12, mx0[g], fmaf(b22, mx1[g], fmaf(b32, mx2[g], t2)));

            if (p < G) {
                float* op = out + (p * BB + (long long)n) * 3;
                op[0] = o0; op[1] = o1; op[2] = o2;
            }
        }
    }
}

extern "C" void kernel_launch(void* const* d_in, const int* in_sizes, int n_in,
                              void* d_out, int out_size, void* d_ws, size_t ws_size,
                              hipStream_t stream) {
    const float* motion_rots    = (const float*)d_in[0];
    const float* motion_transls = (const float*)d_in[1];
    const float* motion_coefs   = (const float*)d_in[2];
    const float* means          = (const float*)d_in[3];
    const int*   ts             = (const int*)d_in[4];
    float* out = (float*)d_out;

    const int G = in_sizes[3] / 3;            // means is (G,3)
    const int F = in_sizes[0] / (6 * KK);     // motion_rots is (K,F,6)

    const int nblk = (G + BLK * GPT - 1) / (BLK * GPT);
    motion_fwd<<<nblk, BLK, 0, stream>>>(motion_rots, motion_transls, motion_coefs,
                                         means, ts, out, G, F);
}